// Round 1
// baseline (38.906 us; speedup 1.0000x reference)
//
#include <hip/hip_runtime.h>
#include <hip/hip_bf16.h>

// Problem constants
#define B_ 4
#define S_ 2048
#define E_ 1024

// Tiling
#define NS_MAX 128            // s-chunks for column-sum partials
#define RB 16                 // reduction chunks for each small GEMM
#define EC (E_ / RB)          // 64 elements per reduction chunk
#define JS (E_ / 256)         // 4 output-column slices per GEMM
#define RPB 16                // rows written per broadcast block

// ---------------------------------------------------------------------------
// K1: partial column sums of value over S.
// pv[b][ns][e] = sum over rows in chunk ns of value[b][s][e]
// grid (nsCount, B_), 256 threads, float4 per thread covers full E row.
// ---------------------------------------------------------------------------
__global__ __launch_bounds__(256) void k_colsum(const float* __restrict__ value,
                                                float* __restrict__ pv,
                                                int nsCount) {
    const int ns = blockIdx.x, b = blockIdx.y;
    const int rows = S_ / nsCount;
    const int t = threadIdx.x;
    const float4* src = reinterpret_cast<const float4*>(
        value + ((size_t)b * S_ + (size_t)ns * rows) * E_);
    float4 acc = make_float4(0.f, 0.f, 0.f, 0.f);
    for (int r = 0; r < rows; ++r) {
        float4 v = src[(size_t)r * (E_ / 4) + t];
        acc.x += v.x; acc.y += v.y; acc.z += v.z; acc.w += v.w;
    }
    reinterpret_cast<float4*>(pv + ((size_t)b * nsCount + ns) * E_)[t] = acc;
}

// ---------------------------------------------------------------------------
// K2: tpart[rb][b][j] = sum_{e in chunk rb} vbar[b][e] * Wv[e][j]
// where vbar[b][e] = sum_ns pv[b][ns][e].
// grid (JS, RB, B_), 256 threads (one per output column j in slice).
// ---------------------------------------------------------------------------
__global__ __launch_bounds__(256) void k_gemm1(const float* __restrict__ pv,
                                               const float* __restrict__ Wv,
                                               float* __restrict__ tpart,
                                               int nsCount) {
    const int js = blockIdx.x, rb = blockIdx.y, b = blockIdx.z;
    const int t = threadIdx.x;
    __shared__ float red[4][EC];
    __shared__ float vbar[EC];

    // Parallel reduce pv over ns for the EC e's of this chunk.
    {
        const int e_l = t & (EC - 1);       // 0..63
        const int grp = t >> 6;             // 0..3
        const int e = rb * EC + e_l;
        float s = 0.f;
        for (int ns = grp; ns < nsCount; ns += 4)
            s += pv[((size_t)b * nsCount + ns) * E_ + e];
        red[grp][e_l] = s;
    }
    __syncthreads();
    if (t < EC) vbar[t] = red[0][t] + red[1][t] + red[2][t] + red[3][t];
    __syncthreads();

    const int j = js * 256 + t;
    const float* w = Wv + (size_t)(rb * EC) * E_ + j;
    float acc = 0.f;
#pragma unroll 8
    for (int ee = 0; ee < EC; ++ee)
        acc = fmaf(vbar[ee], w[(size_t)ee * E_], acc);
    tpart[((size_t)rb * B_ + b) * E_ + j] = acc;
}

// ---------------------------------------------------------------------------
// K3: opart[rb][b][i] = sum_{j in chunk rb} t[b][j] * Wo[j][i]
// where t[b][j] = sum_p tpart[p][b][j] + S*bv[j].
// grid (JS, RB, B_), 256 threads.
// ---------------------------------------------------------------------------
__global__ __launch_bounds__(256) void k_gemm2(const float* __restrict__ tpart,
                                               const float* __restrict__ bv,
                                               const float* __restrict__ Wo,
                                               float* __restrict__ opart) {
    const int is = blockIdx.x, rb = blockIdx.y, b = blockIdx.z;
    const int t = threadIdx.x;
    __shared__ float tj[EC];

    if (t < EC) {
        const int j = rb * EC + t;
        float s = (float)S_ * bv[j];
#pragma unroll
        for (int p = 0; p < RB; ++p)
            s += tpart[((size_t)p * B_ + b) * E_ + j];
        tj[t] = s;
    }
    __syncthreads();

    const int i = is * 256 + t;
    const float* w = Wo + (size_t)(rb * EC) * E_ + i;
    float acc = 0.f;
#pragma unroll 8
    for (int jj = 0; jj < EC; ++jj)
        acc = fmaf(tj[jj], w[(size_t)jj * E_], acc);
    opart[((size_t)rb * B_ + b) * E_ + i] = acc;
}

// ---------------------------------------------------------------------------
// K4: out[b][s][:] = sum_p opart[p][b][:] + bo[:]  broadcast over s.
// grid (S_/RPB, B_), 256 threads, float4 per thread covers full row.
// ---------------------------------------------------------------------------
__global__ __launch_bounds__(256) void k_bcast(const float* __restrict__ opart,
                                               const float* __restrict__ bo,
                                               float* __restrict__ out) {
    const int sb = blockIdx.x, b = blockIdx.y;
    const int t = threadIdx.x;
    float4 o = reinterpret_cast<const float4*>(bo)[t];
#pragma unroll
    for (int p = 0; p < RB; ++p) {
        float4 v = reinterpret_cast<const float4*>(
            opart + ((size_t)p * B_ + b) * E_)[t];
        o.x += v.x; o.y += v.y; o.z += v.z; o.w += v.w;
    }
    float4* dst = reinterpret_cast<float4*>(
        out + ((size_t)b * S_ + (size_t)sb * RPB) * E_);
#pragma unroll
    for (int r = 0; r < RPB; ++r)
        dst[(size_t)r * (E_ / 4) + t] = o;
}

// ---------------------------------------------------------------------------
extern "C" void kernel_launch(void* const* d_in, const int* in_sizes, int n_in,
                              void* d_out, int out_size, void* d_ws, size_t ws_size,
                              hipStream_t stream) {
    // setup_inputs order: query, key, value, Wq, bq, Wk, bk, Wv, bv, Wo, bo
    const float* value = (const float*)d_in[2];
    const float* Wv    = (const float*)d_in[7];
    const float* bv    = (const float*)d_in[8];
    const float* Wo    = (const float*)d_in[9];
    const float* bo    = (const float*)d_in[10];
    float* out = (float*)d_out;

    // Choose NS based on available workspace (deterministic per run).
    const size_t fixed_floats = 2 * (size_t)RB * B_ * E_;   // tpart + opart
    int nsCount = NS_MAX;
    while (nsCount > 16 &&
           ((size_t)B_ * nsCount * E_ + fixed_floats) * sizeof(float) > ws_size)
        nsCount >>= 1;

    float* pv    = (float*)d_ws;
    float* tpart = pv + (size_t)B_ * nsCount * E_;
    float* opart = tpart + (size_t)RB * B_ * E_;

    k_colsum<<<dim3(nsCount, B_), 256, 0, stream>>>(value, pv, nsCount);
    k_gemm1 <<<dim3(JS, RB, B_), 256, 0, stream>>>(pv, Wv, tpart, nsCount);
    k_gemm2 <<<dim3(JS, RB, B_), 256, 0, stream>>>(tpart, bv, Wo, opart);
    k_bcast <<<dim3(S_ / RPB, B_), 256, 0, stream>>>(opart, bo, out);
}

// Round 2
// 32.172 us; speedup vs baseline: 1.2093x; 1.2093x over previous
//
#include <hip/hip_runtime.h>
#include <hip/hip_bf16.h>

// Problem constants
#define B_ 4
#define S_ 2048
#define E_ 1024

// Tiling
#define NS 256                // s-chunks for column-sum partials
#define ROWS (S_ / NS)        // 8 rows per colsum block
#define RB 64                 // reduction chunks for each small GEMV
#define CW 16                 // chunk width (e's or j's per chunk)
#define JS (E_ / 256)         // 4 output-column slices per GEMV
#define RPB 8                 // rows written per broadcast block

// ---------------------------------------------------------------------------
// K1: partial column sums of value over S, plus o[b] = bo init (ns==0 blocks).
// pv[b][ns][e] = sum over 8 rows of value[b][s][e].  grid (NS, B_), 256 thr.
// ---------------------------------------------------------------------------
__global__ __launch_bounds__(256) void k_colsum(const float* __restrict__ value,
                                                const float* __restrict__ bo,
                                                float* __restrict__ pv,
                                                float* __restrict__ o) {
    const int ns = blockIdx.x, b = blockIdx.y;
    const int t = threadIdx.x;
    const float4* src = reinterpret_cast<const float4*>(
        value + ((size_t)b * S_ + (size_t)ns * ROWS) * E_);
    float4 acc = make_float4(0.f, 0.f, 0.f, 0.f);
#pragma unroll
    for (int r = 0; r < ROWS; ++r) {
        float4 v = src[r * (E_ / 4) + t];
        acc.x += v.x; acc.y += v.y; acc.z += v.z; acc.w += v.w;
    }
    reinterpret_cast<float4*>(pv + ((size_t)b * NS + ns) * E_)[t] = acc;
    if (ns == 0) {
        // init o[b][:] = bo[:] so K3 can atomically accumulate
        reinterpret_cast<float4*>(o + (size_t)b * E_)[t] =
            reinterpret_cast<const float4*>(bo)[t];
    }
}

// ---------------------------------------------------------------------------
// K2: tpart[rb][b][j] = sum_{e in 16-chunk rb} vbar[b][e] * Wv[e][j]
// In-block redundant reduce of the 16-e vbar slice from pv.
// grid (JS, RB, B_) = (4,64,4) = 1024 blocks, 256 threads.
// ---------------------------------------------------------------------------
__global__ __launch_bounds__(256) void k_gemm1(const float* __restrict__ pv,
                                               const float* __restrict__ Wv,
                                               float* __restrict__ tpart) {
    const int js = blockIdx.x, rb = blockIdx.y, b = blockIdx.z;
    const int t = threadIdx.x;
    __shared__ float red[16][CW];
    __shared__ float vb[CW];

    // reduce vbar slice [rb*16, rb*16+16) over all NS partials
    {
        const int e_l = t & 15;             // 0..15
        const int g = t >> 4;               // 0..15
        float s = 0.f;
        for (int ns = g; ns < NS; ns += 16)
            s += pv[((size_t)b * NS + ns) * E_ + rb * CW + e_l];
        red[g][e_l] = s;
    }
    __syncthreads();
    if (t < CW) {
        float v = 0.f;
#pragma unroll
        for (int g = 0; g < 16; ++g) v += red[g][t];
        vb[t] = v;
    }
    __syncthreads();

    const int j = js * 256 + t;
    const float* w = Wv + (size_t)(rb * CW) * E_ + j;
    float acc = 0.f;
#pragma unroll
    for (int k = 0; k < CW; ++k)
        acc = fmaf(vb[k], w[(size_t)k * E_], acc);
    tpart[((size_t)rb * B_ + b) * E_ + j] = acc;
}

// ---------------------------------------------------------------------------
// K3: o[b][i] += sum_{j in 16-chunk rb} t[b][j] * Wo[j][i]   (atomicAdd)
// where t[b][j] = sum_p tpart[p][b][j] + S*bv[j], reduced in-block.
// grid (JS, RB, B_) = 1024 blocks, 256 threads.
// ---------------------------------------------------------------------------
__global__ __launch_bounds__(256) void k_gemm2(const float* __restrict__ tpart,
                                               const float* __restrict__ bv,
                                               const float* __restrict__ Wo,
                                               float* __restrict__ o) {
    const int is = blockIdx.x, rb = blockIdx.y, b = blockIdx.z;
    const int t = threadIdx.x;
    __shared__ float red[16][CW];
    __shared__ float tj[CW];

    {
        const int j_l = t & 15;
        const int g = t >> 4;
        float s = 0.f;
#pragma unroll
        for (int p = g; p < RB; p += 16)
            s += tpart[((size_t)p * B_ + b) * E_ + rb * CW + j_l];
        red[g][j_l] = s;
    }
    __syncthreads();
    if (t < CW) {
        float v = (float)S_ * bv[rb * CW + t];
#pragma unroll
        for (int g = 0; g < 16; ++g) v += red[g][t];
        tj[t] = v;
    }
    __syncthreads();

    const int i = is * 256 + t;
    const float* w = Wo + (size_t)(rb * CW) * E_ + i;
    float acc = 0.f;
#pragma unroll
    for (int k = 0; k < CW; ++k)
        acc = fmaf(tj[k], w[(size_t)k * E_], acc);
    atomicAdd(&o[(size_t)b * E_ + i], acc);
}

// ---------------------------------------------------------------------------
// K4: out[b][s][:] = o[b][:] broadcast over s.  grid (S_/RPB, B_), 256 thr.
// ---------------------------------------------------------------------------
__global__ __launch_bounds__(256) void k_bcast(const float* __restrict__ o,
                                               float* __restrict__ out) {
    const int sb = blockIdx.x, b = blockIdx.y;
    const int t = threadIdx.x;
    float4 ov = reinterpret_cast<const float4*>(o + (size_t)b * E_)[t];
    float4* dst = reinterpret_cast<float4*>(
        out + ((size_t)b * S_ + (size_t)sb * RPB) * E_);
#pragma unroll
    for (int r = 0; r < RPB; ++r)
        dst[r * (E_ / 4) + t] = ov;
}

// ---------------------------------------------------------------------------
extern "C" void kernel_launch(void* const* d_in, const int* in_sizes, int n_in,
                              void* d_out, int out_size, void* d_ws, size_t ws_size,
                              hipStream_t stream) {
    // setup_inputs order: query, key, value, Wq, bq, Wk, bk, Wv, bv, Wo, bo
    const float* value = (const float*)d_in[2];
    const float* Wv    = (const float*)d_in[7];
    const float* bv    = (const float*)d_in[8];
    const float* Wo    = (const float*)d_in[9];
    const float* bo    = (const float*)d_in[10];
    float* out = (float*)d_out;

    float* pv    = (float*)d_ws;                       // [B][NS][E]   4 MB
    float* tpart = pv + (size_t)B_ * NS * E_;          // [RB][B][E]   1 MB
    float* o     = tpart + (size_t)RB * B_ * E_;       // [B][E]       16 KB

    k_colsum<<<dim3(NS, B_),        256, 0, stream>>>(value, bo, pv, o);
    k_gemm1 <<<dim3(JS, RB, B_),    256, 0, stream>>>(pv, Wv, tpart);
    k_gemm2 <<<dim3(JS, RB, B_),    256, 0, stream>>>(tpart, bv, Wo, o);
    k_bcast <<<dim3(S_ / RPB, B_),  256, 0, stream>>>(o, out);
}